// Round 1
// baseline (14435.783 us; speedup 1.0000x reference)
//
#include <hip/hip_runtime.h>
#include <hip/hip_fp16.h>

typedef unsigned short u16;
typedef _Float16 f16x8 __attribute__((ext_vector_type(8)));
typedef float f32x4 __attribute__((ext_vector_type(4)));

#define VV   96
#define DD   256
#define NSL  24
#define HH   512
#define LL   2
#define BB   64
#define TT   128

__device__ __forceinline__ u16 f2h(float f){ return __half_as_ushort(__float2half(f)); }
__device__ __forceinline__ float h2f(u16 u){ return __half2float(__ushort_as_half(u)); }
__device__ __forceinline__ float gelu_f(float x){ return 0.5f*x*(1.f+erff(x*0.70710678118654752f)); }
__device__ __forceinline__ float sigm_f(float x){ return 1.f/(1.f+__expf(-x)); }
__device__ __forceinline__ float tanh_f(float x){
  x = fminf(15.f, fmaxf(-15.f, x));
  float e2 = __expf(2.f*x);
  return (e2-1.f)/(e2+1.f);
}

// dot of f16 weight row (global) with fp32 vector (LDS), K multiple of 8
__device__ __forceinline__ float dot_row(const u16* __restrict__ row, const float* __restrict__ v, int K){
  float acc = 0.f;
  for(int k=0;k<K;k+=8){
    uint4 w = *(const uint4*)(row + k);
    float4 a  = *(const float4*)(v + k);
    float4 bq = *(const float4*)(v + k + 4);
    float2 f0 = __half22float2(*(const __half2*)&w.x);
    float2 f1 = __half22float2(*(const __half2*)&w.y);
    float2 f2_ = __half22float2(*(const __half2*)&w.z);
    float2 f3 = __half22float2(*(const __half2*)&w.w);
    acc += f0.x*a.x + f0.y*a.y + f1.x*a.z + f1.y*a.w;
    acc += f2_.x*bq.x + f2_.y*bq.y + f3.x*bq.z + f3.y*bq.w;
  }
  return acc;
}

// ---------- prep kernels: fp32 -> f16, optionally transposed ----------
__global__ void k_cvt(const float* __restrict__ s, u16* __restrict__ d, int n){
  int i = blockIdx.x*256 + threadIdx.x;
  if(i<n) d[i] = f2h(s[i]);
}
// src [K][N] -> dst [N][K]
__global__ void k_cvtT(const float* __restrict__ s, u16* __restrict__ d, int K, int N){
  int i = blockIdx.x*256 + threadIdx.x;
  if(i < K*N){ int k = i/N, n = i - k*N; d[n*K + k] = f2h(s[i]); }
}

// ---------- LN over 256 elems, all 512 threads participate ----------
__device__ __forceinline__ void layernorm256(float* __restrict__ dst, const float* __restrict__ src,
    const float* __restrict__ g, const float* __restrict__ bta, float* __restrict__ red, int tid){
  float v = (tid < DD) ? src[tid] : 0.f;
  float s1 = v, s2 = v*v;
  #pragma unroll
  for(int o=32;o>0;o>>=1){ s1 += __shfl_down(s1,o,64); s2 += __shfl_down(s2,o,64); }
  if((tid&63)==0){ red[tid>>6] = s1; red[8+(tid>>6)] = s2; }
  __syncthreads();
  if(tid==0){
    float a=0.f,c=0.f;
    #pragma unroll
    for(int i=0;i<8;++i){ a+=red[i]; c+=red[8+i]; }
    float m = a*(1.f/DD);
    float var = c*(1.f/DD) - m*m;
    red[16]=m; red[17]=rsqrtf(var+1e-5f);
  }
  __syncthreads();
  if(tid<DD) dst[tid] = (src[tid]-red[16])*red[17]*g[tid] + bta[tid];
  __syncthreads();
}

__global__ __launch_bounds__(512) void ssr_main(
    const int* __restrict__ x, const float* __restrict__ emb, const float* __restrict__ pos,
    const u16* __restrict__ r1T, const float* __restrict__ b_r1,
    const u16* __restrict__ r2T, const float* __restrict__ b_r2,
    const u16* __restrict__ wihW, const u16* __restrict__ whhW,
    const float* __restrict__ bih, const float* __restrict__ bhh,
    const u16* __restrict__ pjT, const float* __restrict__ b_pj,
    const float* __restrict__ g1, const float* __restrict__ be1,
    const u16* __restrict__ f1T, const float* __restrict__ b_f1,
    const u16* __restrict__ f2T, const float* __restrict__ b_f2,
    const float* __restrict__ g2, const float* __restrict__ be2,
    const float* __restrict__ go, const float* __restrict__ bo,
    const u16* __restrict__ hdT, const float* __restrict__ b_hd,
    float* __restrict__ out)
{
  extern __shared__ float sm[];
  float* S    = sm;            // 12288  (L*NS*D) fp32 slot state
  float* gx   = sm + 12288;    // 768
  float* xv   = sm + 13056;    // 256
  float* ctx  = sm + 13312;    // 512
  float* hmid = sm + 13824;    // 256
  float* alpha= sm + 14080;    // 32
  float* sctx = sm + 14112;    // 256
  float* xm   = sm + 14368;    // 256
  float* h1   = sm + 14624;    // 256
  float* ff   = sm + 14880;    // 512
  float* red  = sm + 15392;    // 64
  u16*  gh16  = (u16*)(sm + 15456); // 24*768 = 18432 u16
  u16*  sbf   = (u16*)(sm + 24672); // 32*264 = 8448 u16 (padded rows, rows>=24 zero)
  // total 28896 floats = 115584 B

  const int b = blockIdx.x;
  const int tid = threadIdx.x;

  for(int i=tid;i<LL*NSL*DD;i+=512) S[i]=0.f;
  __syncthreads();

  for(int t=0;t<TT;++t){
    const int tok = x[b*TT + t];
    for(int d=tid; d<DD; d+=512) xv[d] = emb[tok*DD+d] + pos[t*DD+d];
    __syncthreads();

    for(int li=0; li<LL; ++li){
      float* Sl = S + li*NSL*DD;
      // ---- ctx = [xv, slot_mean(S_prev)]
      if(tid < DD){
        float s_=0.f;
        #pragma unroll
        for(int j=0;j<NSL;++j) s_ += Sl[j*DD+tid];
        ctx[DD+tid] = s_ * (1.f/NSL);
        ctx[tid] = xv[tid];
      }
      __syncthreads();
      // ---- route1: hmid = gelu(ctx @ W1 + b1), K=512 split over 2 halves
      {
        int d = tid & (DD-1), hf = tid >> 8;
        const u16* row = r1T + ((li*DD + d)*(2*DD)) + hf*DD;
        ff[tid] = dot_row(row, ctx + hf*DD, DD);
      }
      __syncthreads();
      if(tid<DD) hmid[tid] = gelu_f(ff[tid] + ff[DD+tid] + b_r1[li*DD+tid]);
      __syncthreads();
      // ---- route2 (24 outputs, K=256 split 8-way)
      if(tid < 192){
        int s_ = tid>>3, p = tid&7;
        const u16* row = r2T + (li*NSL + s_)*DD + p*32;
        ff[tid] = dot_row(row, hmid + p*32, 32);
      }
      __syncthreads();
      if(tid < NSL){
        float lg = b_r2[li*NSL+tid];
        #pragma unroll
        for(int p=0;p<8;++p) lg += ff[tid*8+p];
        alpha[tid] = lg;
      }
      __syncthreads();
      if(tid==0){ // softmax over 24 (TAU=1)
        float m=-1e30f;
        for(int s_=0;s_<NSL;++s_) m = fmaxf(m, alpha[s_]);
        float sum=0.f;
        for(int s_=0;s_<NSL;++s_){ float e=__expf(alpha[s_]-m); alpha[s_]=e; sum+=e; }
        float inv = 1.f/sum;
        for(int s_=0;s_<NSL;++s_) alpha[s_]*=inv;
      }
      // ---- gx[e] = xv . wih[e,:]  (raw dot, bias added in GRU phase)
      {
        const u16* W = wihW + li*3*DD*DD;
        for(int e=tid; e<3*DD; e+=512) gx[e] = dot_row(W + e*DD, xv, DD);
      }
      // ---- S -> f16 (padded to 32 rows for MFMA)
      for(int i=tid; i<32*DD; i+=512){
        int s_ = i>>8, d = i & (DD-1);
        sbf[s_*264+d] = (s_<NSL) ? f2h(Sl[s_*DD+d]) : (u16)0;
      }
      __syncthreads();
      // ---- gh = S @ whh^T via mfma 16x16x32 f16 (M=2x16 covering 24 slots, N=48x16, K=8x32)
      {
        const int l = tid & 63, w = tid >> 6;
        const int lr = l & 15, lk = l >> 4;
        const u16* WB = whhW + li*3*DD*DD;
        const u16* a0p = sbf + lr*264 + lk*8;
        const u16* a1p = sbf + (16+lr)*264 + lk*8;
        for(int nt=w; nt<48; nt+=8){
          const u16* bp = WB + (nt*16 + lr)*DD + lk*8;
          f32x4 acc0 = {0.f,0.f,0.f,0.f}, acc1 = {0.f,0.f,0.f,0.f};
          #pragma unroll
          for(int ks=0; ks<8; ++ks){
            f16x8 bfr = *(const f16x8*)(bp + ks*32);
            f16x8 a0  = *(const f16x8*)(a0p + ks*32);
            f16x8 a1  = *(const f16x8*)(a1p + ks*32);
            acc0 = __builtin_amdgcn_mfma_f32_16x16x32_f16(a0, bfr, acc0, 0,0,0);
            acc1 = __builtin_amdgcn_mfma_f32_16x16x32_f16(a1, bfr, acc1, 0,0,0);
          }
          #pragma unroll
          for(int r=0;r<4;++r){
            int s0 = lk*4 + r;                 // D row = (lane>>4)*4+reg, col = lane&15
            gh16[s0*768 + nt*16 + lr] = f2h(acc0[r]);
            int s1 = 16 + lk*4 + r;
            if(s1 < NSL) gh16[s1*768 + nt*16 + lr] = f2h(acc1[r]);
          }
        }
      }
      __syncthreads();
      // ---- GRU update + slot_ctx partials
      {
        int d = tid & (DD-1), so = tid >> 8;
        const float* bihL = bih + li*3*DD;
        const float* bhhL = bhh + li*3*DD;
        float gir = gx[d], giz = gx[DD+d], gin = gx[2*DD+d];
        float bir = bihL[d], biz = bihL[DD+d], bin = bihL[2*DD+d];
        float bhr = bhhL[d], bhz = bhhL[DD+d], bhn = bhhL[2*DD+d];
        float pctx = 0.f;
        for(int j=0;j<NSL/2;++j){
          int s_ = 2*j + so;
          float al = alpha[s_];
          float hr = h2f(gh16[s_*768+d])      + bhr;
          float hz = h2f(gh16[s_*768+DD+d])   + bhz;
          float hn = h2f(gh16[s_*768+2*DD+d]) + bhn;
          float rr = sigm_f(al*gir + bir + hr);
          float zz = sigm_f(al*giz + biz + hz);
          float nn = tanh_f(al*gin + bin + rr*hn);
          float sv = Sl[s_*DD+d];
          float ns = (1.f-zz)*nn + zz*sv;
          Sl[s_*DD+d] = ns;
          pctx += al*ns;
        }
        ff[tid] = pctx;
      }
      __syncthreads();
      if(tid<DD) sctx[tid] = ff[tid] + ff[DD+tid];
      __syncthreads();
      // ---- proj
      {
        int d = tid & (DD-1), hf = tid >> 8;
        const u16* row = pjT + (li*DD + d)*DD + hf*128;
        ff[tid] = dot_row(row, sctx + hf*128, 128);
      }
      __syncthreads();
      if(tid<DD) xm[tid] = xv[tid] + b_pj[li*DD+tid] + ff[tid] + ff[DD+tid];
      __syncthreads();
      // ---- LN1
      layernorm256(h1, xm, g1+li*DD, be1+li*DD, red, tid);
      // ---- ffn1 (512 outputs, K=256)
      {
        const u16* row = f1T + (li*HH + tid)*DD;
        float a = dot_row(row, h1, DD) + b_f1[li*HH+tid];
        ff[tid] = gelu_f(a);
      }
      __syncthreads();
      // ---- ffn2 (256 outputs, K=512 split 2)
      {
        int d = tid & (DD-1), hf = tid >> 8;
        const u16* row = f2T + (li*DD + d)*HH + hf*DD;
        gx[tid] = dot_row(row, ff + hf*DD, DD);
      }
      __syncthreads();
      if(tid<DD) xm[tid] = xm[tid] + b_f2[li*DD+tid] + gx[tid] + gx[DD+tid];
      __syncthreads();
      // ---- LN2 -> xv (next layer input)
      layernorm256(xv, xm, g2+li*DD, be2+li*DD, red, tid);
    } // layers

    // ---- head: LN + [96 x 256] GEMV
    layernorm256(h1, xv, go, bo, red, tid);
    if(tid < 384){
      int v = tid>>2, q = tid&3;
      const u16* row = hdT + v*DD + q*64;
      ff[tid] = dot_row(row, h1 + q*64, 64);
    }
    __syncthreads();
    if(tid < VV){
      float lg = b_hd[tid] + ff[tid*4] + ff[tid*4+1] + ff[tid*4+2] + ff[tid*4+3];
      out[((size_t)b*TT + t)*VV + tid] = lg;
    }
    __syncthreads();
  }
}

extern "C" void kernel_launch(void* const* d_in, const int* in_sizes, int n_in,
                              void* d_out, int out_size, void* d_ws, size_t ws_size,
                              hipStream_t stream){
  const int*   x    = (const int*)  d_in[0];
  const float* emb  = (const float*)d_in[1];
  const float* pos  = (const float*)d_in[2];
  const float* r1   = (const float*)d_in[3];
  const float* br1  = (const float*)d_in[4];
  const float* r2   = (const float*)d_in[5];
  const float* br2  = (const float*)d_in[6];
  const float* wih  = (const float*)d_in[7];
  const float* whh  = (const float*)d_in[8];
  const float* bih  = (const float*)d_in[9];
  const float* bhh  = (const float*)d_in[10];
  const float* pj   = (const float*)d_in[11];
  const float* bpj  = (const float*)d_in[12];
  const float* g1   = (const float*)d_in[13];
  const float* be1  = (const float*)d_in[14];
  const float* f1   = (const float*)d_in[15];
  const float* bf1  = (const float*)d_in[16];
  const float* f2   = (const float*)d_in[17];
  const float* bf2  = (const float*)d_in[18];
  const float* g2   = (const float*)d_in[19];
  const float* be2  = (const float*)d_in[20];
  const float* go   = (const float*)d_in[21];
  const float* bo   = (const float*)d_in[22];
  const float* hd   = (const float*)d_in[23];
  const float* bhd  = (const float*)d_in[24];
  float* out = (float*)d_out;
  u16* ws = (u16*)d_ws;

  // f16 weight sections in workspace (element offsets)
  u16* r1T  = ws + 0;        // L*256*512
  u16* r2T  = ws + 262144;   // L*24*256
  u16* wihW = ws + 274432;   // L*768*256 (row-major as given)
  u16* whhW = ws + 667648;   // L*768*256 (row-major as given)
  u16* pjT  = ws + 1060864;  // L*256*256
  u16* f1T  = ws + 1191936;  // L*512*256
  u16* f2T  = ws + 1454080;  // L*256*512
  u16* hdT  = ws + 1716224;  // 96*256    -> total 1740800 u16 = 3.48 MB

  k_cvt<<<(2*768*256+255)/256,256,0,stream>>>(wih, wihW, 2*768*256);
  k_cvt<<<(2*768*256+255)/256,256,0,stream>>>(whh, whhW, 2*768*256);
  for(int li=0; li<2; ++li){
    k_cvtT<<<(512*256+255)/256,256,0,stream>>>(r1 + li*512*256, r1T + li*256*512, 512, 256);
    k_cvtT<<<(256*24+255)/256, 256,0,stream>>>(r2 + li*256*24,  r2T + li*24*256,  256, 24);
    k_cvtT<<<(256*256+255)/256,256,0,stream>>>(pj + li*256*256, pjT + li*256*256, 256, 256);
    k_cvtT<<<(256*512+255)/256,256,0,stream>>>(f1 + li*256*512, f1T + li*512*256, 256, 512);
    k_cvtT<<<(512*256+255)/256,256,0,stream>>>(f2 + li*512*256, f2T + li*256*512, 512, 256);
  }
  k_cvtT<<<(256*96+255)/256,256,0,stream>>>(hd, hdT, 256, 96);

  const int smem = 28896*4;
  hipFuncSetAttribute(reinterpret_cast<const void*>(ssr_main),
                      hipFuncAttributeMaxDynamicSharedMemorySize, smem);
  ssr_main<<<BB, 512, smem, stream>>>(x, emb, pos, r1T, br1, r2T, br2, wihW, whhW, bih, bhh,
                                      pjT, bpj, g1, be1, f1T, bf1, f2T, bf2, g2, be2, go, bo,
                                      hdT, bhd, out);
}

// Round 2
// 9727.464 us; speedup vs baseline: 1.4840x; 1.4840x over previous
//
#include <hip/hip_runtime.h>
#include <hip/hip_fp16.h>

typedef unsigned short u16;
typedef _Float16 f16x8 __attribute__((ext_vector_type(8)));
typedef float f32x4 __attribute__((ext_vector_type(4)));

#define VV   96
#define DD   256
#define NSL  24
#define HH   512
#define LL   2
#define BB   64
#define TT   128

__device__ __forceinline__ u16 f2h(float f){ return __half_as_ushort(__float2half(f)); }
__device__ __forceinline__ float h2f(u16 u){ return __half2float(__ushort_as_half(u)); }
__device__ __forceinline__ float gelu_f(float x){ return 0.5f*x*(1.f+erff(x*0.70710678118654752f)); }
__device__ __forceinline__ float sigm_f(float x){ return 1.f/(1.f+__expf(-x)); }
__device__ __forceinline__ float tanh_f(float x){
  x = fminf(15.f, fmaxf(-15.f, x));
  float e2 = __expf(2.f*x);
  return (e2-1.f)/(e2+1.f);
}

// grouped GEMV: 8 lanes per output row. Lane g loads 16B chunks at (it*8+g)*8
// elements -> 8 consecutive lanes read 128B contiguous (full line utilization).
// v is LDS, read as 8-way same-address broadcast across groups (no conflict).
__device__ __forceinline__ float dotg8(const u16* __restrict__ row, const float* __restrict__ v,
                                       int g, int iters){
  float acc = 0.f;
  #pragma unroll
  for(int it=0; it<iters; ++it){
    int k = (it*8 + g)*8;
    uint4 w = *(const uint4*)(row + k);
    float4 a  = *(const float4*)(v + k);
    float4 bq = *(const float4*)(v + k + 4);
    float2 f0 = __half22float2(*(const __half2*)&w.x);
    float2 f1 = __half22float2(*(const __half2*)&w.y);
    float2 f2_ = __half22float2(*(const __half2*)&w.z);
    float2 f3 = __half22float2(*(const __half2*)&w.w);
    acc += f0.x*a.x + f0.y*a.y + f1.x*a.z + f1.y*a.w;
    acc += f2_.x*bq.x + f2_.y*bq.y + f3.x*bq.z + f3.y*bq.w;
  }
  return acc;
}
__device__ __forceinline__ float red8(float acc){
  acc += __shfl_down(acc,4,64);
  acc += __shfl_down(acc,2,64);
  acc += __shfl_down(acc,1,64);
  return acc;
}

// ---------- prep kernels: fp32 -> f16, optionally transposed ----------
__global__ void k_cvt(const float* __restrict__ s, u16* __restrict__ d, int n){
  int i = blockIdx.x*256 + threadIdx.x;
  if(i<n) d[i] = f2h(s[i]);
}
// src [K][N] -> dst [N][K]
__global__ void k_cvtT(const float* __restrict__ s, u16* __restrict__ d, int K, int N){
  int i = blockIdx.x*256 + threadIdx.x;
  if(i < K*N){ int k = i/N, n = i - k*N; d[n*K + k] = f2h(s[i]); }
}

// ---------- LN over 256 elems ----------
__device__ __forceinline__ void layernorm256(float* __restrict__ dst, const float* __restrict__ src,
    const float* __restrict__ g, const float* __restrict__ bta, float* __restrict__ red, int tid){
  float v = (tid < DD) ? src[tid] : 0.f;
  float s1 = v, s2 = v*v;
  #pragma unroll
  for(int o=32;o>0;o>>=1){ s1 += __shfl_down(s1,o,64); s2 += __shfl_down(s2,o,64); }
  if((tid&63)==0){ red[tid>>6] = s1; red[8+(tid>>6)] = s2; }
  __syncthreads();
  if(tid==0){
    float a=0.f,c=0.f;
    #pragma unroll
    for(int i=0;i<8;++i){ a+=red[i]; c+=red[8+i]; }
    float m = a*(1.f/DD);
    float var = c*(1.f/DD) - m*m;
    red[16]=m; red[17]=rsqrtf(var+1e-5f);
  }
  __syncthreads();
  if(tid<DD) dst[tid] = (src[tid]-red[16])*red[17]*g[tid] + bta[tid];
  __syncthreads();
}

__global__ __launch_bounds__(512) void ssr_main(
    const int* __restrict__ x, const float* __restrict__ emb, const float* __restrict__ pos,
    const u16* __restrict__ r1T, const float* __restrict__ b_r1,
    const u16* __restrict__ r2T, const float* __restrict__ b_r2,
    const u16* __restrict__ wihW, const u16* __restrict__ whhW,
    const float* __restrict__ bih, const float* __restrict__ bhh,
    const u16* __restrict__ pjT, const float* __restrict__ b_pj,
    const float* __restrict__ g1, const float* __restrict__ be1,
    const u16* __restrict__ f1T, const float* __restrict__ b_f1,
    const u16* __restrict__ f2T, const float* __restrict__ b_f2,
    const float* __restrict__ g2, const float* __restrict__ be2,
    const float* __restrict__ go, const float* __restrict__ bo,
    const u16* __restrict__ hdT, const float* __restrict__ b_hd,
    float* __restrict__ out)
{
  extern __shared__ float sm[];
  float* S    = sm;            // 12288  (L*NS*D) fp32 slot state
  float* gx   = sm + 12288;    // 768
  float* xv   = sm + 13056;    // 256
  float* ctx  = sm + 13312;    // 512
  float* hmid = sm + 13824;    // 256
  float* alpha= sm + 14080;    // 32
  float* sctx = sm + 14112;    // 256
  float* xm   = sm + 14368;    // 256
  float* h1   = sm + 14624;    // 256
  float* ff   = sm + 14880;    // 512
  float* red  = sm + 15392;    // 64
  u16*  gh16  = (u16*)(sm + 15456); // 24*768 = 18432 u16
  u16*  sbf   = (u16*)(sm + 24672); // 32*264 = 8448 u16 (padded rows, rows>=24 zero)
  // total 28896 floats = 115584 B

  const int b = blockIdx.x;
  const int tid = threadIdx.x;
  const int g = tid & 7, gid = tid >> 3;   // 64 groups of 8 lanes

  for(int i=tid;i<LL*NSL*DD;i+=512) S[i]=0.f;
  __syncthreads();

  for(int t=0;t<TT;++t){
    const int tok = x[b*TT + t];
    for(int d=tid; d<DD; d+=512) xv[d] = emb[tok*DD+d] + pos[t*DD+d];
    __syncthreads();

    for(int li=0; li<LL; ++li){
      float* Sl = S + li*NSL*DD;
      // ---- ctx = [xv, slot_mean(S_prev)]
      if(tid < DD){
        float s_=0.f;
        #pragma unroll
        for(int j=0;j<NSL;++j) s_ += Sl[j*DD+tid];
        ctx[DD+tid] = s_ * (1.f/NSL);
        ctx[tid] = xv[tid];
      }
      __syncthreads();
      // ---- route1: hmid = gelu(ctx @ W1 + b1)  [256 outs, K=512]
      #pragma unroll
      for(int p=0;p<4;++p){
        int d = p*64 + gid;
        const u16* row = r1T + (size_t)(li*DD + d)*(2*DD);
        float acc = red8(dotg8(row, ctx, g, 8));
        if(!g) hmid[d] = gelu_f(acc + b_r1[li*DD+d]);
      }
      __syncthreads();
      // ---- route2 (24 outs, K=256)
      if(gid < NSL){
        const u16* row = r2T + (size_t)(li*NSL + gid)*DD;
        float acc = red8(dotg8(row, hmid, g, 4));
        if(!g) alpha[gid] = acc + b_r2[li*NSL+gid];
      }
      __syncthreads();
      if(tid==0){ // softmax over 24 (TAU=1)
        float m=-1e30f;
        for(int s_=0;s_<NSL;++s_) m = fmaxf(m, alpha[s_]);
        float sum=0.f;
        for(int s_=0;s_<NSL;++s_){ float e=__expf(alpha[s_]-m); alpha[s_]=e; sum+=e; }
        float inv = 1.f/sum;
        for(int s_=0;s_<NSL;++s_) alpha[s_]*=inv;
      }
      // ---- gx[e] = xv . wih[e,:]  [768 outs, K=256]
      {
        const u16* W = wihW + (size_t)li*3*DD*DD;
        #pragma unroll
        for(int p=0;p<12;++p){
          int n = p*64 + gid;
          float acc = red8(dotg8(W + (size_t)n*DD, xv, g, 4));
          if(!g) gx[n] = acc;
        }
      }
      // ---- S -> f16 (padded to 32 rows for MFMA)
      for(int i=tid; i<32*DD; i+=512){
        int s_ = i>>8, d = i & (DD-1);
        sbf[s_*264+d] = (s_<NSL) ? f2h(Sl[s_*DD+d]) : (u16)0;
      }
      __syncthreads();
      // ---- gh = S @ whh^T via mfma 16x16x32 f16 (M=2x16, N=48x16, K=8x32)
      {
        const int l = tid & 63, w = tid >> 6;
        const int lr = l & 15, lk = l >> 4;
        const u16* WB = whhW + (size_t)li*3*DD*DD;
        const u16* a0p = sbf + lr*264 + lk*8;
        const u16* a1p = sbf + (16+lr)*264 + lk*8;
        for(int nt=w; nt<48; nt+=8){
          const u16* bp = WB + (size_t)(nt*16 + lr)*DD + lk*8;
          f32x4 acc0 = {0.f,0.f,0.f,0.f}, acc1 = {0.f,0.f,0.f,0.f};
          #pragma unroll
          for(int ks=0; ks<8; ++ks){
            f16x8 bfr = *(const f16x8*)(bp + ks*32);
            f16x8 a0  = *(const f16x8*)(a0p + ks*32);
            f16x8 a1  = *(const f16x8*)(a1p + ks*32);
            acc0 = __builtin_amdgcn_mfma_f32_16x16x32_f16(a0, bfr, acc0, 0,0,0);
            acc1 = __builtin_amdgcn_mfma_f32_16x16x32_f16(a1, bfr, acc1, 0,0,0);
          }
          #pragma unroll
          for(int r=0;r<4;++r){
            int s0 = lk*4 + r;                 // row=(lane>>4)*4+reg, col=lane&15
            gh16[s0*768 + nt*16 + lr] = f2h(acc0[r]);
            int s1 = 16 + lk*4 + r;
            if(s1 < NSL) gh16[s1*768 + nt*16 + lr] = f2h(acc1[r]);
          }
        }
      }
      __syncthreads();
      // ---- GRU update + slot_ctx partials
      {
        int d = tid & (DD-1), so = tid >> 8;
        const float* bihL = bih + li*3*DD;
        const float* bhhL = bhh + li*3*DD;
        float gir = gx[d], giz = gx[DD+d], gin = gx[2*DD+d];
        float bir = bihL[d], biz = bihL[DD+d], bin = bihL[2*DD+d];
        float bhr = bhhL[d], bhz = bhhL[DD+d], bhn = bhhL[2*DD+d];
        float pctx = 0.f;
        for(int j=0;j<NSL/2;++j){
          int s_ = 2*j + so;
          float al = alpha[s_];
          float hr = h2f(gh16[s_*768+d])      + bhr;
          float hz = h2f(gh16[s_*768+DD+d])   + bhz;
          float hn = h2f(gh16[s_*768+2*DD+d]) + bhn;
          float rr = sigm_f(al*gir + bir + hr);
          float zz = sigm_f(al*giz + biz + hz);
          float nn = tanh_f(al*gin + bin + rr*hn);
          float sv = Sl[s_*DD+d];
          float ns = (1.f-zz)*nn + zz*sv;
          Sl[s_*DD+d] = ns;
          pctx += al*ns;
        }
        ff[tid] = pctx;
      }
      __syncthreads();
      if(tid<DD) sctx[tid] = ff[tid] + ff[DD+tid];
      __syncthreads();
      // ---- proj [256 outs, K=256] -> xm = xv + proj(sctx) + b
      #pragma unroll
      for(int p=0;p<4;++p){
        int d = p*64 + gid;
        const u16* row = pjT + (size_t)(li*DD + d)*DD;
        float acc = red8(dotg8(row, sctx, g, 4));
        if(!g) xm[d] = xv[d] + b_pj[li*DD+d] + acc;
      }
      __syncthreads();
      // ---- LN1
      layernorm256(h1, xm, g1+li*DD, be1+li*DD, red, tid);
      // ---- ffn1 [512 outs, K=256]
      #pragma unroll
      for(int p=0;p<8;++p){
        int n = p*64 + gid;
        const u16* row = f1T + (size_t)(li*HH + n)*DD;
        float acc = red8(dotg8(row, h1, g, 4));
        if(!g) ff[n] = gelu_f(acc + b_f1[li*HH+n]);
      }
      __syncthreads();
      // ---- ffn2 [256 outs, K=512]
      #pragma unroll
      for(int p=0;p<4;++p){
        int d = p*64 + gid;
        const u16* row = f2T + (size_t)(li*DD + d)*HH;
        float acc = red8(dotg8(row, ff, g, 8));
        if(!g) xm[d] = xm[d] + b_f2[li*DD+d] + acc;
      }
      __syncthreads();
      // ---- LN2 -> xv (next layer input)
      layernorm256(xv, xm, g2+li*DD, be2+li*DD, red, tid);
    } // layers

    // ---- head: LN + [96 x 256] GEMV
    layernorm256(h1, xv, go, bo, red, tid);
    {
      float* outp = out + ((size_t)b*TT + t)*VV;
      int n = gid;
      float acc = red8(dotg8(hdT + (size_t)n*DD, h1, g, 4));
      if(!g && n < VV) outp[n] = acc + b_hd[n];
      if(gid < VV-64){
        n = 64 + gid;
        acc = red8(dotg8(hdT + (size_t)n*DD, h1, g, 4));
        if(!g) outp[n] = acc + b_hd[n];
      }
    }
    __syncthreads();
  }
}

extern "C" void kernel_launch(void* const* d_in, const int* in_sizes, int n_in,
                              void* d_out, int out_size, void* d_ws, size_t ws_size,
                              hipStream_t stream){
  const int*   x    = (const int*)  d_in[0];
  const float* emb  = (const float*)d_in[1];
  const float* pos  = (const float*)d_in[2];
  const float* r1   = (const float*)d_in[3];
  const float* br1  = (const float*)d_in[4];
  const float* r2   = (const float*)d_in[5];
  const float* br2  = (const float*)d_in[6];
  const float* wih  = (const float*)d_in[7];
  const float* whh  = (const float*)d_in[8];
  const float* bih  = (const float*)d_in[9];
  const float* bhh  = (const float*)d_in[10];
  const float* pj   = (const float*)d_in[11];
  const float* bpj  = (const float*)d_in[12];
  const float* g1   = (const float*)d_in[13];
  const float* be1  = (const float*)d_in[14];
  const float* f1   = (const float*)d_in[15];
  const float* bf1  = (const float*)d_in[16];
  const float* f2   = (const float*)d_in[17];
  const float* bf2  = (const float*)d_in[18];
  const float* g2   = (const float*)d_in[19];
  const float* be2  = (const float*)d_in[20];
  const float* go   = (const float*)d_in[21];
  const float* bo   = (const float*)d_in[22];
  const float* hd   = (const float*)d_in[23];
  const float* bhd  = (const float*)d_in[24];
  float* out = (float*)d_out;
  u16* ws = (u16*)d_ws;

  // f16 weight sections in workspace (element offsets)
  u16* r1T  = ws + 0;        // L*256*512
  u16* r2T  = ws + 262144;   // L*24*256
  u16* wihW = ws + 274432;   // L*768*256 (row-major as given)
  u16* whhW = ws + 667648;   // L*768*256 (row-major as given)
  u16* pjT  = ws + 1060864;  // L*256*256
  u16* f1T  = ws + 1191936;  // L*512*256
  u16* f2T  = ws + 1454080;  // L*256*512
  u16* hdT  = ws + 1716224;  // 96*256    -> total 1740800 u16 = 3.48 MB

  k_cvt<<<(2*768*256+255)/256,256,0,stream>>>(wih, wihW, 2*768*256);
  k_cvt<<<(2*768*256+255)/256,256,0,stream>>>(whh, whhW, 2*768*256);
  for(int li=0; li<2; ++li){
    k_cvtT<<<(512*256+255)/256,256,0,stream>>>(r1 + li*512*256, r1T + li*256*512, 512, 256);
    k_cvtT<<<(256*24+255)/256, 256,0,stream>>>(r2 + li*256*24,  r2T + li*24*256,  256, 24);
    k_cvtT<<<(256*256+255)/256,256,0,stream>>>(pj + li*256*256, pjT + li*256*256, 256, 256);
    k_cvtT<<<(256*512+255)/256,256,0,stream>>>(f1 + li*256*512, f1T + li*512*256, 256, 512);
    k_cvtT<<<(512*256+255)/256,256,0,stream>>>(f2 + li*512*256, f2T + li*256*512, 512, 256);
  }
  k_cvtT<<<(256*96+255)/256,256,0,stream>>>(hd, hdT, 256, 96);

  const int smem = 28896*4;
  hipFuncSetAttribute(reinterpret_cast<const void*>(ssr_main),
                      hipFuncAttributeMaxDynamicSharedMemorySize, smem);
  ssr_main<<<BB, 512, smem, stream>>>(x, emb, pos, r1T, br1, r2T, br2, wihW, whhW, bih, bhh,
                                      pjT, bpj, g1, be1, f1T, bf1, f2T, bf2, g2, be2, go, bo,
                                      hdT, bhd, out);
}